// Round 8
// baseline (677.494 us; speedup 1.0000x reference)
//
#include <hip/hip_runtime.h>

// Dual-key attention, bf16 MFMA pipeline. ws_size >= 42 MiB.
// ws layout (MiB offsets):
//   0: qbf   [b][h][1024][64] bf16   (8 MiB)
//   8: khat  [b][h][1024][64] bf16   (8)
//  16: vT    [b][h][64][1024] bf16   (8)
//  24: attno [b*1024+n][h*64+d] bf16 (8)
//  32: WqT,Wk1T,Wk2T,WvT,WoT bf16 [N][K] (2 MiB each)

typedef short bf16x8 __attribute__((ext_vector_type(8)));
typedef float f32x4 __attribute__((ext_vector_type(4)));

__device__ __forceinline__ unsigned short f2bf(float f) {
  unsigned int u = __float_as_uint(f);
  return (unsigned short)((u + 0x7FFFu + ((u >> 16) & 1u)) >> 16);
}

__device__ __forceinline__ float bf2f(unsigned short u) {
  return __uint_as_float((unsigned)u << 16);
}

__device__ __forceinline__ bf16x8 pack8(float4 a, float4 b) {
  bf16x8 r;
  r[0] = (short)f2bf(a.x); r[1] = (short)f2bf(a.y);
  r[2] = (short)f2bf(a.z); r[3] = (short)f2bf(a.w);
  r[4] = (short)f2bf(b.x); r[5] = (short)f2bf(b.y);
  r[6] = (short)f2bf(b.z); r[7] = (short)f2bf(b.w);
  return r;
}

__device__ __forceinline__ void gload_lds16(const void* g, void* l) {
  __builtin_amdgcn_global_load_lds(
      (const __attribute__((address_space(1))) unsigned int*)g,
      (__attribute__((address_space(3))) unsigned int*)l, 16, 0, 0);
}

// ---------------- batched W [1024][1024] fp32 -> W^T bf16 (5 weights) -------
struct W5 { const float *w0, *w1, *w2, *w3, *w4; };

__global__ __launch_bounds__(256) void transpose5_kernel(W5 w, unsigned short* out) {
  __shared__ float tile[32][33];
  const int z = blockIdx.z;
  const float* in = (z == 0) ? w.w0 : (z == 1) ? w.w1 : (z == 2) ? w.w2
                    : (z == 3) ? w.w3 : w.w4;
  unsigned short* o = out + (size_t)z * (1024 * 1024);
  const int x = threadIdx.x & 31;
  const int y0 = (threadIdx.x >> 5) << 2;
  const int r0 = blockIdx.y * 32, c0 = blockIdx.x * 32;
#pragma unroll
  for (int i = 0; i < 4; ++i)
    tile[y0 + i][x] = in[(size_t)(r0 + y0 + i) * 1024 + c0 + x];
  __syncthreads();
#pragma unroll
  for (int i = 0; i < 4; ++i) {
    int c = y0 + i;
    o[(size_t)(c0 + c) * 1024 + r0 + x] = f2bf(tile[x][c]);
  }
}

// ---------------- 64x64-tile, BK=64 MFMA GEMM: C = A1@B1^T (+A2@B2^T) + bias
// AMODE 0: A fp32 (converted during reg-staging). AMODE 1: A bf16 (gload_lds).
// B: [N][K] bf16 (W^T). Double-buffered LDS, XOR-swizzled rows, 1 barrier/phase.
// omode 0: bf16 out [b][h][n][64]; 1: bf16 out [b][h][64][n]; 2: fp32 [M][N].
template <int AMODE>
__global__ __launch_bounds__(256, 4) void gemm64_kernel(
    const void* A1v, const unsigned short* __restrict__ B1,
    const void* A2v, const unsigned short* __restrict__ B2,
    const float* __restrict__ bias1, const float* __restrict__ bias2,
    void* __restrict__ outp, int M, int N, int K, int omode) {
  __shared__ unsigned short lA[2][64 * 64];
  __shared__ unsigned short lB[2][64 * 64];
  const int tid = threadIdx.x;
  const int lane = tid & 63, wave = tid >> 6;
  const int l15 = lane & 15, lg = lane >> 4;
  const int m0 = blockIdx.x * 64, n0 = blockIdx.y * 64;
  const int wr = wave >> 1, wc = wave & 1;  // 2x2 waves, 32x32 each
  const int arow = tid >> 2;                 // A staging row 0..63
  const int acb = (tid & 3) * 32;            // A staging col byte 0..96

  f32x4 zero4 = {0.f, 0.f, 0.f, 0.f};
  f32x4 acc[2][2];
#pragma unroll
  for (int i = 0; i < 2; ++i)
#pragma unroll
    for (int j = 0; j < 2; ++j) acc[i][j] = zero4;

  const int ksteps = K >> 6;
  const int npair = (A2v != nullptr) ? 2 : 1;
  const int nsteps = npair * ksteps;

  // ---- prologue: stage phase 0 into buf 0 ----
  {
#pragma unroll
    for (int rep = 0; rep < 2; ++rep) {
      int c = rep * 256 + tid;
      int row = c >> 3;
      int off = ((c & 7) * 16) ^ ((row & 7) << 4);
      gload_lds16(&B1[(size_t)(n0 + row) * K + (off >> 1)],
                  (char*)lB[0] + rep * 4096 + wave * 1024);
      if (AMODE == 1)
        gload_lds16(&((const unsigned short*)A1v)[(size_t)(m0 + row) * K + (off >> 1)],
                    (char*)lA[0] + rep * 4096 + wave * 1024);
    }
    if (AMODE == 0) {
      const float* A = (const float*)A1v;
      const int ce = acb >> 1;  // col elem base
      float4 a0 = *(const float4*)&A[(size_t)(m0 + arow) * K + ce];
      float4 a1 = *(const float4*)&A[(size_t)(m0 + arow) * K + ce + 4];
      float4 a2 = *(const float4*)&A[(size_t)(m0 + arow) * K + ce + 8];
      float4 a3 = *(const float4*)&A[(size_t)(m0 + arow) * K + ce + 12];
      int sw = (arow & 7) << 4;
      *(bf16x8*)((char*)lA[0] + arow * 128 + (acb ^ sw)) = pack8(a0, a1);
      *(bf16x8*)((char*)lA[0] + arow * 128 + ((acb + 16) ^ sw)) = pack8(a2, a3);
    }
  }
  __syncthreads();

  for (int s = 0; s < nsteps; ++s) {
    const int cur = s & 1, nxt = cur ^ 1;
    const bool hn = (s + 1 < nsteps);
    float4 a0, a1, a2, a3;
    if (hn) {
      const int s1 = s + 1;
      const int p1 = (s1 >= ksteps) ? 1 : 0;
      const int k1 = (s1 - p1 * ksteps) * 64;
      const unsigned short* B = p1 ? B2 : B1;
#pragma unroll
      for (int rep = 0; rep < 2; ++rep) {
        int c = rep * 256 + tid;
        int row = c >> 3;
        int off = ((c & 7) * 16) ^ ((row & 7) << 4);
        gload_lds16(&B[(size_t)(n0 + row) * K + k1 + (off >> 1)],
                    (char*)lB[nxt] + rep * 4096 + wave * 1024);
        if (AMODE == 1)
          gload_lds16(&((const unsigned short*)(p1 ? A2v : A1v))
                          [(size_t)(m0 + row) * K + k1 + (off >> 1)],
                      (char*)lA[nxt] + rep * 4096 + wave * 1024);
      }
      if (AMODE == 0) {
        const float* A = (const float*)(p1 ? A2v : A1v);
        const int ce = k1 + (acb >> 1);
        a0 = *(const float4*)&A[(size_t)(m0 + arow) * K + ce];
        a1 = *(const float4*)&A[(size_t)(m0 + arow) * K + ce + 4];
        a2 = *(const float4*)&A[(size_t)(m0 + arow) * K + ce + 8];
        a3 = *(const float4*)&A[(size_t)(m0 + arow) * K + ce + 12];
      }
    }
    // fragments + 8 MFMA on cur
    bf16x8 af[2][2], bfr[2][2];
#pragma unroll
    for (int mf = 0; mf < 2; ++mf) {
      int row = wr * 32 + mf * 16 + l15;
      int sw = (row & 7) << 4;
#pragma unroll
      for (int kk = 0; kk < 2; ++kk)
        af[mf][kk] = *(const bf16x8*)((const char*)lA[cur] + row * 128 +
                                      ((kk * 64 + lg * 16) ^ sw));
    }
#pragma unroll
    for (int nf = 0; nf < 2; ++nf) {
      int row = wc * 32 + nf * 16 + l15;
      int sw = (row & 7) << 4;
#pragma unroll
      for (int kk = 0; kk < 2; ++kk)
        bfr[nf][kk] = *(const bf16x8*)((const char*)lB[cur] + row * 128 +
                                       ((kk * 64 + lg * 16) ^ sw));
    }
#pragma unroll
    for (int kk = 0; kk < 2; ++kk)
#pragma unroll
      for (int mf = 0; mf < 2; ++mf)
#pragma unroll
        for (int nf = 0; nf < 2; ++nf)
          acc[mf][nf] = __builtin_amdgcn_mfma_f32_16x16x32_bf16(
              af[mf][kk], bfr[nf][kk], acc[mf][nf], 0, 0, 0);
    if (AMODE == 0 && hn) {  // lA[nxt] safe: last read a phase ago, pre-barrier
      int sw = (arow & 7) << 4;
      *(bf16x8*)((char*)lA[nxt] + arow * 128 + (acb ^ sw)) = pack8(a0, a1);
      *(bf16x8*)((char*)lA[nxt] + arow * 128 + ((acb + 16) ^ sw)) = pack8(a2, a3);
    }
    __syncthreads();  // drains vmcnt (B/A DMA) + lgkm (A writes); cur reads done
  }

  unsigned short* outb = (unsigned short*)outp;
  float* outf = (float*)outp;
#pragma unroll
  for (int mf = 0; mf < 2; ++mf) {
#pragma unroll
    for (int nf = 0; nf < 2; ++nf) {
      int cg = n0 + wc * 32 + nf * 16 + l15;
      float badd = (bias1 ? bias1[cg] : 0.f) + (bias2 ? bias2[cg] : 0.f);
#pragma unroll
      for (int j = 0; j < 4; ++j) {
        int r = m0 + wr * 32 + mf * 16 + lg * 4 + j;
        float v = acc[mf][nf][j] + badd;
        if (omode == 2) {
          outf[(size_t)r * N + cg] = v;
        } else {
          int bb = r >> 10, nn = r & 1023;
          int hh = cg >> 6, dd = cg & 63;
          if (omode == 0)
            outb[(((size_t)bb * 16 + hh) * 1024 + nn) * 64 + dd] = f2bf(v);
          else
            outb[(((size_t)bb * 16 + hh) * 64 + dd) * 1024 + nn] = f2bf(v);
        }
      }
    }
  }
}

// ---------------- fused dual-key attention (kt-split across waves) ---------
// 4096 blocks = (bh, 16-q-row group). Wave w handles kt in [4w, 4w+4) with
// r5's proven barrier-free direct-read loop (K/V served from L2 via XCD
// swizzle; VGPR=64, zero conflicts). One barrier total: 4-way flash-merge of
// (m, l, O) partials via LDS (O partials bf16). 8 blocks/CU -> 100% occ cap.
__global__ __launch_bounds__(256, 8) void attn_kernel(
    const unsigned short* __restrict__ q, const unsigned short* __restrict__ kh,
    const unsigned short* __restrict__ vT, const float* __restrict__ aw,
    const void* __restrict__ msk, unsigned short* __restrict__ attnout) {
  __shared__ unsigned short lP[4][16 * 64];  // per-wave P tile, swizzled rows
  __shared__ unsigned short lO[3][16 * 64];  // waves 1-3 partial O (bf16)
  __shared__ float lml[3][32];               // waves 1-3: m[0:16], l[16:32]

  const int tid = threadIdx.x, lane = tid & 63, wave = tid >> 6;
  const int l15 = lane & 15, lg = lane >> 4;
  // XCD swizzle (4096 % 8 == 0, bijective): XCD k serves 8 bh -> its K/V
  // working set (8 x 256 KB) fits the 4 MB per-XCD L2.
  const int bid = blockIdx.x;
  const int swb = (bid & 7) * 512 + (bid >> 3);
  const int bh = swb >> 6, qg = swb & 63;
  const int b = bh >> 4, h = bh & 15;
  const int qbase = qg * 16;

  // mask dtype detection (wave-uniform): i32 0/1 words are always <=1
  unsigned w0 = ((const unsigned*)msk)[lane];
  const bool mbyte = (__ballot(w0 > 1u) != 0ull);
  const unsigned char* mp8 = (const unsigned char*)msk + (size_t)bh * 1048576;
  const int* mpi = (const int*)msk + (size_t)bh * 1048576;

  const unsigned short* qp = q + (size_t)bh * 65536;
  const unsigned short* kp = kh + (size_t)bh * 65536;
  const unsigned short* vp = vT + (size_t)bh * 65536;
  const float* awp = aw + (size_t)bh * 1048576;

  bf16x8 qf[2];
#pragma unroll
  for (int kk = 0; kk < 2; ++kk)
    qf[kk] = *(const bf16x8*)&qp[(qbase + l15) * 64 + kk * 32 + lg * 8];

  f32x4 zero4 = {0.f, 0.f, 0.f, 0.f};
  f32x4 oacc[4];
  float mrun[4], lrun[4];
#pragma unroll
  for (int x = 0; x < 4; ++x) {
    oacc[x] = zero4;
    mrun[x] = -1e30f;
    lrun[x] = 0.f;
  }

  const float scale = 0.08838834764831845f;  // 1/sqrt(128)

  for (int it = 0; it < 4; ++it) {
    const int kt = wave * 4 + it;
    // ---- K fragments + aw + mask loads (independent, long latency) ----
    bf16x8 kf[2][4];
#pragma unroll
    for (int kk = 0; kk < 2; ++kk)
#pragma unroll
      for (int nf = 0; nf < 4; ++nf)
        kf[kk][nf] = *(const bf16x8*)&kp[(size_t)(kt * 64 + nf * 16 + l15) * 64 +
                                         kk * 32 + lg * 8];
    float awc[4][4];
    unsigned mkc[4];
#pragma unroll
    for (int j = 0; j < 4; ++j) {
      const int r = qbase + lg * 4 + j;
      const float* awrow = awp + (size_t)r * 1024 + kt * 64;
      const size_t mb = (size_t)r * 1024 + kt * 64;
      unsigned mk = 0;
      if (mbyte) {
#pragma unroll
        for (int nf = 0; nf < 4; ++nf) {
          awc[j][nf] = awrow[nf * 16 + l15];
          mk |= ((unsigned)mp8[mb + nf * 16 + l15] & 1u) << nf;
        }
      } else {
#pragma unroll
        for (int nf = 0; nf < 4; ++nf) {
          awc[j][nf] = awrow[nf * 16 + l15];
          mk |= ((unsigned)(mpi[mb + nf * 16 + l15] != 0)) << nf;
        }
      }
      mkc[j] = mk;
    }

    // ---- S = Q @ K^T ----
    f32x4 sacc[4];
#pragma unroll
    for (int nf = 0; nf < 4; ++nf) sacc[nf] = zero4;
#pragma unroll
    for (int kk = 0; kk < 2; ++kk)
#pragma unroll
      for (int nf = 0; nf < 4; ++nf)
        sacc[nf] = __builtin_amdgcn_mfma_f32_16x16x32_bf16(qf[kk], kf[kk][nf],
                                                           sacc[nf], 0, 0, 0);

    // ---- V fragments issued before softmax (latency hidden under VALU) ----
    bf16x8 vf[2][4];
#pragma unroll
    for (int kk = 0; kk < 2; ++kk)
#pragma unroll
      for (int df = 0; df < 4; ++df)
        vf[kk][df] = *(const bf16x8*)&vp[(size_t)(df * 16 + l15) * 1024 +
                                         kt * 64 + kk * 32 + lg * 8];

    // ---- scale*aw, mask, online softmax; write P straight to LDS ----
    float alpha[4];
#pragma unroll
    for (int j = 0; j < 4; ++j) {
      float mx = -1e30f;
#pragma unroll
      for (int nf = 0; nf < 4; ++nf) {
        float s = sacc[nf][j] * scale * awc[j][nf];
        s = ((mkc[j] >> nf) & 1u) ? -1e30f : s;
        sacc[nf][j] = s;
        mx = fmaxf(mx, s);
      }
      mx = fmaxf(mx, __shfl_xor(mx, 1));
      mx = fmaxf(mx, __shfl_xor(mx, 2));
      mx = fmaxf(mx, __shfl_xor(mx, 4));
      mx = fmaxf(mx, __shfl_xor(mx, 8));
      float mnew = fmaxf(mrun[j], mx);
      float al = __expf(mrun[j] - mnew);
      mrun[j] = mnew;
      float psum = 0.f;
      const int prow = lg * 4 + j;
      const int swp = (prow & 7) << 4;
#pragma unroll
      for (int nf = 0; nf < 4; ++nf) {
        float s = sacc[nf][j];
        float p = (s <= -1e29f) ? 0.f : __expf(s - mnew);
        psum += p;
        *(unsigned short*)((char*)lP[wave] + prow * 128 +
                           (((nf * 16 + l15) * 2) ^ swp)) = f2bf(p);
      }
      psum += __shfl_xor(psum, 1);
      psum += __shfl_xor(psum, 2);
      psum += __shfl_xor(psum, 4);
      psum += __shfl_xor(psum, 8);
      lrun[j] = lrun[j] * al + psum;
      alpha[j] = al;
    }
#pragma unroll
    for (int df = 0; df < 4; ++df)
#pragma unroll
      for (int j = 0; j < 4; ++j) oacc[df][j] *= alpha[j];

    // ---- O += P @ V ----
#pragma unroll
    for (int kk2 = 0; kk2 < 2; ++kk2) {
      bf16x8 pf;
      {
        int off = (kk2 * 64 + lg * 16) ^ ((l15 & 7) << 4);
        pf = *(const bf16x8*)((const char*)lP[wave] + l15 * 128 + off);
      }
#pragma unroll
      for (int df = 0; df < 4; ++df)
        oacc[df] = __builtin_amdgcn_mfma_f32_16x16x32_bf16(pf, vf[kk2][df],
                                                           oacc[df], 0, 0, 0);
    }
  }

  // ---- 4-way flash-merge across waves ----
  if (wave != 0) {
#pragma unroll
    for (int j = 0; j < 4; ++j) {
      if (l15 == 0) {
        lml[wave - 1][lg * 4 + j] = mrun[j];
        lml[wave - 1][16 + lg * 4 + j] = lrun[j];
      }
#pragma unroll
      for (int df = 0; df < 4; ++df)
        lO[wave - 1][(lg * 4 + j) * 64 + df * 16 + l15] = f2bf(oacc[df][j]);
    }
  }
  __syncthreads();
  if (wave == 0) {
#pragma unroll
    for (int j = 0; j < 4; ++j) {
      const int row = lg * 4 + j;
      float m1 = lml[0][row], m2 = lml[1][row], m3 = lml[2][row];
      float l1 = lml[0][16 + row], l2 = lml[1][16 + row], l3 = lml[2][16 + row];
      float M = fmaxf(fmaxf(mrun[j], m1), fmaxf(m2, m3));
      float a0 = __expf(mrun[j] - M), a1 = __expf(m1 - M);
      float a2 = __expf(m2 - M), a3 = __expf(m3 - M);
      float L = lrun[j] * a0 + l1 * a1 + l2 * a2 + l3 * a3;
      float inv = 1.0f / L;
#pragma unroll
      for (int df = 0; df < 4; ++df) {
        int c = df * 16 + l15;
        float o = oacc[df][j] * a0 + bf2f(lO[0][row * 64 + c]) * a1 +
                  bf2f(lO[1][row * 64 + c]) * a2 + bf2f(lO[2][row * 64 + c]) * a3;
        attnout[(size_t)(b * 1024 + qbase + row) * 1024 + h * 64 + c] =
            f2bf(o * inv);
      }
    }
  }
}

extern "C" void kernel_launch(void* const* d_in, const int* in_sizes, int n_in,
                              void* d_out, int out_size, void* d_ws, size_t ws_size,
                              hipStream_t stream) {
  const float* queries = (const float*)d_in[0];
  const float* keys1 = (const float*)d_in[1];
  const float* keys2 = (const float*)d_in[2];
  const float* values = (const float*)d_in[3];
  const float* aw = (const float*)d_in[4];
  const void* mask = d_in[5];
  const float* Wq = (const float*)d_in[6];
  const float* bq = (const float*)d_in[7];
  const float* Wk1 = (const float*)d_in[8];
  const float* bk1 = (const float*)d_in[9];
  const float* Wk2 = (const float*)d_in[10];
  const float* bk2 = (const float*)d_in[11];
  const float* Wv = (const float*)d_in[12];
  const float* bv = (const float*)d_in[13];
  const float* Wo = (const float*)d_in[14];
  const float* bo = (const float*)d_in[15];

  char* ws = (char*)d_ws;
  unsigned short* qbf = (unsigned short*)(ws + (0ull << 20));
  unsigned short* khat = (unsigned short*)(ws + (8ull << 20));
  unsigned short* vTb = (unsigned short*)(ws + (16ull << 20));
  unsigned short* attno = (unsigned short*)(ws + (24ull << 20));
  unsigned short* WT = (unsigned short*)(ws + (32ull << 20));
  unsigned short* WqT = WT;
  unsigned short* Wk1T = WT + 1 * 1048576;
  unsigned short* Wk2T = WT + 2 * 1048576;
  unsigned short* WvT = WT + 3 * 1048576;
  unsigned short* WoT = WT + 4 * 1048576;

  transpose5_kernel<<<dim3(32, 32, 5), 256, 0, stream>>>(
      W5{Wq, Wk1, Wk2, Wv, Wo}, WT);

  const dim3 gg(64, 16);  // M/64, N/64
  gemm64_kernel<0><<<gg, 256, 0, stream>>>(queries, WqT, nullptr, nullptr,
                                           bq, nullptr, qbf, 4096, 1024, 1024, 0);
  gemm64_kernel<0><<<gg, 256, 0, stream>>>(keys1, Wk1T, keys2, Wk2T,
                                           bk1, bk2, khat, 4096, 1024, 1024, 0);
  gemm64_kernel<0><<<gg, 256, 0, stream>>>(values, WvT, nullptr, nullptr,
                                           bv, nullptr, vTb, 4096, 1024, 1024, 1);

  attn_kernel<<<4096, 256, 0, stream>>>(qbf, khat, vTb, aw, mask, attno);

  gemm64_kernel<1><<<gg, 256, 0, stream>>>(attno, WoT, nullptr, nullptr,
                                           bo, nullptr, d_out, 4096, 1024, 1024, 2);
}

// Round 10
// 500.217 us; speedup vs baseline: 1.3544x; 1.3544x over previous
//
#include <hip/hip_runtime.h>

// Dual-key attention, bf16 MFMA pipeline. ws_size >= 51 MiB.
// ws layout (MiB offsets):
//   0: qbf   [b][h][1024][64] bf16   (8 MiB)
//   8: khat  [b][h][1024][64] bf16   (8)
//  16: vT    [b][h][64][1024] bf16   (8)
//  24: attno [b*1024+n][h*64+d] bf16 (8)
//  32: WoT bf16 (2)
//  34: WqT, 36: Wk1T, 38: Wk2T, 40: WvT (2 each; dead after projections ->
//       overwritten by attn partials:)
//  34: Opart[2][bh*1024+q][64] bf16 (16 MiB total)
//  50: stats[2][bh*1024+q] float2   (1 MiB)

typedef short bf16x8 __attribute__((ext_vector_type(8)));
typedef float f32x4 __attribute__((ext_vector_type(4)));

__device__ __forceinline__ unsigned short f2bf(float f) {
  unsigned int u = __float_as_uint(f);
  return (unsigned short)((u + 0x7FFFu + ((u >> 16) & 1u)) >> 16);
}

__device__ __forceinline__ float bf2f(unsigned short u) {
  return __uint_as_float((unsigned)u << 16);
}

__device__ __forceinline__ bf16x8 pack8(float4 a, float4 b) {
  bf16x8 r;
  r[0] = (short)f2bf(a.x); r[1] = (short)f2bf(a.y);
  r[2] = (short)f2bf(a.z); r[3] = (short)f2bf(a.w);
  r[4] = (short)f2bf(b.x); r[5] = (short)f2bf(b.y);
  r[6] = (short)f2bf(b.z); r[7] = (short)f2bf(b.w);
  return r;
}

__device__ __forceinline__ void gload_lds16(const void* g, void* l) {
  __builtin_amdgcn_global_load_lds(
      (const __attribute__((address_space(1))) unsigned int*)g,
      (__attribute__((address_space(3))) unsigned int*)l, 16, 0, 0);
}

// ---------------- batched W [1024][1024] fp32 -> W^T bf16 (5 weights) -------
struct W5 { const float *w0, *w1, *w2, *w3, *w4; };

__global__ __launch_bounds__(256) void transpose5_kernel(W5 w, unsigned short* out) {
  __shared__ float tile[32][33];
  const int z = blockIdx.z;
  const float* in = (z == 0) ? w.w0 : (z == 1) ? w.w1 : (z == 2) ? w.w2
                    : (z == 3) ? w.w3 : w.w4;
  unsigned short* o = out + (size_t)z * (1024 * 1024);
  const int x = threadIdx.x & 31;
  const int y0 = (threadIdx.x >> 5) << 2;
  const int r0 = blockIdx.y * 32, c0 = blockIdx.x * 32;
#pragma unroll
  for (int i = 0; i < 4; ++i)
    tile[y0 + i][x] = in[(size_t)(r0 + y0 + i) * 1024 + c0 + x];
  __syncthreads();
#pragma unroll
  for (int i = 0; i < 4; ++i) {
    int c = y0 + i;
    o[(size_t)(c0 + c) * 1024 + r0 + x] = f2bf(tile[x][c]);
  }
}

// ---------------- 64x64-tile, BK=64 MFMA GEMM: C = A1@B1^T (+A2@B2^T) + bias
template <int AMODE>
__global__ __launch_bounds__(256, 4) void gemm64_kernel(
    const void* A1v, const unsigned short* __restrict__ B1,
    const void* A2v, const unsigned short* __restrict__ B2,
    const float* __restrict__ bias1, const float* __restrict__ bias2,
    void* __restrict__ outp, int M, int N, int K, int omode) {
  __shared__ unsigned short lA[2][64 * 64];
  __shared__ unsigned short lB[2][64 * 64];
  const int tid = threadIdx.x;
  const int lane = tid & 63, wave = tid >> 6;
  const int l15 = lane & 15, lg = lane >> 4;
  const int m0 = blockIdx.x * 64, n0 = blockIdx.y * 64;
  const int wr = wave >> 1, wc = wave & 1;
  const int arow = tid >> 2;
  const int acb = (tid & 3) * 32;

  f32x4 zero4 = {0.f, 0.f, 0.f, 0.f};
  f32x4 acc[2][2];
#pragma unroll
  for (int i = 0; i < 2; ++i)
#pragma unroll
    for (int j = 0; j < 2; ++j) acc[i][j] = zero4;

  const int ksteps = K >> 6;
  const int npair = (A2v != nullptr) ? 2 : 1;
  const int nsteps = npair * ksteps;

  {
#pragma unroll
    for (int rep = 0; rep < 2; ++rep) {
      int c = rep * 256 + tid;
      int row = c >> 3;
      int off = ((c & 7) * 16) ^ ((row & 7) << 4);
      gload_lds16(&B1[(size_t)(n0 + row) * K + (off >> 1)],
                  (char*)lB[0] + rep * 4096 + wave * 1024);
      if (AMODE == 1)
        gload_lds16(&((const unsigned short*)A1v)[(size_t)(m0 + row) * K + (off >> 1)],
                    (char*)lA[0] + rep * 4096 + wave * 1024);
    }
    if (AMODE == 0) {
      const float* A = (const float*)A1v;
      const int ce = acb >> 1;
      float4 a0 = *(const float4*)&A[(size_t)(m0 + arow) * K + ce];
      float4 a1 = *(const float4*)&A[(size_t)(m0 + arow) * K + ce + 4];
      float4 a2 = *(const float4*)&A[(size_t)(m0 + arow) * K + ce + 8];
      float4 a3 = *(const float4*)&A[(size_t)(m0 + arow) * K + ce + 12];
      int sw = (arow & 7) << 4;
      *(bf16x8*)((char*)lA[0] + arow * 128 + (acb ^ sw)) = pack8(a0, a1);
      *(bf16x8*)((char*)lA[0] + arow * 128 + ((acb + 16) ^ sw)) = pack8(a2, a3);
    }
  }
  __syncthreads();

  for (int s = 0; s < nsteps; ++s) {
    const int cur = s & 1, nxt = cur ^ 1;
    const bool hn = (s + 1 < nsteps);
    float4 a0, a1, a2, a3;
    if (hn) {
      const int s1 = s + 1;
      const int p1 = (s1 >= ksteps) ? 1 : 0;
      const int k1 = (s1 - p1 * ksteps) * 64;
      const unsigned short* B = p1 ? B2 : B1;
#pragma unroll
      for (int rep = 0; rep < 2; ++rep) {
        int c = rep * 256 + tid;
        int row = c >> 3;
        int off = ((c & 7) * 16) ^ ((row & 7) << 4);
        gload_lds16(&B[(size_t)(n0 + row) * K + k1 + (off >> 1)],
                    (char*)lB[nxt] + rep * 4096 + wave * 1024);
        if (AMODE == 1)
          gload_lds16(&((const unsigned short*)(p1 ? A2v : A1v))
                          [(size_t)(m0 + row) * K + k1 + (off >> 1)],
                      (char*)lA[nxt] + rep * 4096 + wave * 1024);
      }
      if (AMODE == 0) {
        const float* A = (const float*)(p1 ? A2v : A1v);
        const int ce = k1 + (acb >> 1);
        a0 = *(const float4*)&A[(size_t)(m0 + arow) * K + ce];
        a1 = *(const float4*)&A[(size_t)(m0 + arow) * K + ce + 4];
        a2 = *(const float4*)&A[(size_t)(m0 + arow) * K + ce + 8];
        a3 = *(const float4*)&A[(size_t)(m0 + arow) * K + ce + 12];
      }
    }
    bf16x8 af[2][2], bfr[2][2];
#pragma unroll
    for (int mf = 0; mf < 2; ++mf) {
      int row = wr * 32 + mf * 16 + l15;
      int sw = (row & 7) << 4;
#pragma unroll
      for (int kk = 0; kk < 2; ++kk)
        af[mf][kk] = *(const bf16x8*)((const char*)lA[cur] + row * 128 +
                                      ((kk * 64 + lg * 16) ^ sw));
    }
#pragma unroll
    for (int nf = 0; nf < 2; ++nf) {
      int row = wc * 32 + nf * 16 + l15;
      int sw = (row & 7) << 4;
#pragma unroll
      for (int kk = 0; kk < 2; ++kk)
        bfr[nf][kk] = *(const bf16x8*)((const char*)lB[cur] + row * 128 +
                                       ((kk * 64 + lg * 16) ^ sw));
    }
#pragma unroll
    for (int kk = 0; kk < 2; ++kk)
#pragma unroll
      for (int mf = 0; mf < 2; ++mf)
#pragma unroll
        for (int nf = 0; nf < 2; ++nf)
          acc[mf][nf] = __builtin_amdgcn_mfma_f32_16x16x32_bf16(
              af[mf][kk], bfr[nf][kk], acc[mf][nf], 0, 0, 0);
    if (AMODE == 0 && hn) {
      int sw = (arow & 7) << 4;
      *(bf16x8*)((char*)lA[nxt] + arow * 128 + (acb ^ sw)) = pack8(a0, a1);
      *(bf16x8*)((char*)lA[nxt] + arow * 128 + ((acb + 16) ^ sw)) = pack8(a2, a3);
    }
    __syncthreads();
  }

  unsigned short* outb = (unsigned short*)outp;
  float* outf = (float*)outp;
#pragma unroll
  for (int mf = 0; mf < 2; ++mf) {
#pragma unroll
    for (int nf = 0; nf < 2; ++nf) {
      int cg = n0 + wc * 32 + nf * 16 + l15;
      float badd = (bias1 ? bias1[cg] : 0.f) + (bias2 ? bias2[cg] : 0.f);
#pragma unroll
      for (int j = 0; j < 4; ++j) {
        int r = m0 + wr * 32 + mf * 16 + lg * 4 + j;
        float v = acc[mf][nf][j] + badd;
        if (omode == 2) {
          outf[(size_t)r * N + cg] = v;
        } else {
          int bb = r >> 10, nn = r & 1023;
          int hh = cg >> 6, dd = cg & 63;
          if (omode == 0)
            outb[(((size_t)bb * 16 + hh) * 1024 + nn) * 64 + dd] = f2bf(v);
          else
            outb[(((size_t)bb * 16 + hh) * 64 + dd) * 1024 + nn] = f2bf(v);
        }
      }
    }
  }
}

// ---------------- fused dual-key attention (r3 loop, kt-split x2) ----------
// 2048 blocks: swb = bh(64) x half(2) x qt16(16). 4 waves x 16 q-rows cover
// a 64-row q-group; each block iterates 8 of 16 K-tiles (KVBLK=64). K staged
// dbuf via global_load_lds (16KB LDS); V direct from global (L2-resident via
// XCD swizzle); per-wave P tile (8KB). LDS 24KB -> 6 blocks/CU at (256,6).
// Partial (m,l,O) written to workspace; merged by merge_kernel.
__global__ __launch_bounds__(256, 6) void attn_kernel(
    const unsigned short* __restrict__ q, const unsigned short* __restrict__ kh,
    const unsigned short* __restrict__ vT, const float* __restrict__ aw,
    const void* __restrict__ msk, unsigned short* __restrict__ opart,
    float2* __restrict__ stats) {
  __shared__ unsigned short lK[2][64 * 64];  // [k][d] 128B rows, XOR-swizzled
  __shared__ unsigned short lP[4][16 * 64];  // per-wave P tile, swizzled

  const int tid = threadIdx.x, lane = tid & 63, wave = tid >> 6;
  const int l15 = lane & 15, lg = lane >> 4;
  // XCD swizzle (2048 % 8 == 0): each XCD gets 256 consecutive swb = 8 bh ->
  // K/V working set 8 x 256 KB = 2 MB fits the 4 MB per-XCD L2.
  const int bid = blockIdx.x;
  const int swb = (bid & 7) * 256 + (bid >> 3);
  const int bh = swb >> 5;            // [0,64)
  const int half = (swb >> 4) & 1;    // [0,2)
  const int qt16 = swb & 15;          // [0,16)
  const int b = bh >> 4, h = bh & 15;
  const int qrow0 = qt16 * 64 + wave * 16;

  // mask dtype detection (wave-uniform): i32 0/1 words are always <=1
  unsigned w0 = ((const unsigned*)msk)[lane];
  const bool mbyte = (__ballot(w0 > 1u) != 0ull);
  const unsigned char* mp8 = (const unsigned char*)msk + (size_t)bh * 1048576;
  const int* mpi = (const int*)msk + (size_t)bh * 1048576;

  const unsigned short* qp = q + (size_t)bh * 65536;
  const unsigned short* kp = kh + (size_t)bh * 65536;
  const unsigned short* vp = vT + (size_t)bh * 65536;
  const float* awp = aw + (size_t)bh * 1048576;

  bf16x8 qf[2];
#pragma unroll
  for (int kk = 0; kk < 2; ++kk)
    qf[kk] = *(const bf16x8*)&qp[(qrow0 + l15) * 64 + kk * 32 + lg * 8];

  f32x4 zero4 = {0.f, 0.f, 0.f, 0.f};
  f32x4 oacc[4];
  float mrun[4], lrun[4];
#pragma unroll
  for (int x = 0; x < 4; ++x) {
    oacc[x] = zero4;
    mrun[x] = -1e30f;
    lrun[x] = 0.f;
  }

  const float scale = 0.08838834764831845f;  // 1/sqrt(128)
  const int kt0 = half * 8;

  // prologue: stage tile kt0 into buf 0
#pragma unroll
  for (int rep = 0; rep < 2; ++rep) {
    int c = rep * 256 + tid;
    int row = c >> 3;
    int off = ((c & 7) * 16) ^ ((row & 7) << 4);
    gload_lds16(&kp[(size_t)(kt0 * 64 + row) * 64 + (off >> 1)],
                (char*)lK[0] + rep * 4096 + wave * 1024);
  }
  __syncthreads();

  for (int it = 0; it < 8; ++it) {
    const int kt = kt0 + it;
    const int cur = it & 1, nxt = cur ^ 1;
    if (it < 7) {
#pragma unroll
      for (int rep = 0; rep < 2; ++rep) {
        int c = rep * 256 + tid;
        int row = c >> 3;
        int off = ((c & 7) * 16) ^ ((row & 7) << 4);
        gload_lds16(&kp[(size_t)((kt + 1) * 64 + row) * 64 + (off >> 1)],
                    (char*)lK[nxt] + rep * 4096 + wave * 1024);
      }
    }

    // aw/mask loads issued early (longest latency; independent of LDS)
    float awc[4][4];
    unsigned mkc[4];
#pragma unroll
    for (int j = 0; j < 4; ++j) {
      const int r = qrow0 + lg * 4 + j;
      const float* awrow = awp + (size_t)r * 1024 + kt * 64;
      const size_t mb = (size_t)r * 1024 + kt * 64;
      unsigned mk = 0;
      if (mbyte) {
#pragma unroll
        for (int nf = 0; nf < 4; ++nf) {
          awc[j][nf] = awrow[nf * 16 + l15];
          mk |= ((unsigned)mp8[mb + nf * 16 + l15] & 1u) << nf;
        }
      } else {
#pragma unroll
        for (int nf = 0; nf < 4; ++nf) {
          awc[j][nf] = awrow[nf * 16 + l15];
          mk |= ((unsigned)(mpi[mb + nf * 16 + l15] != 0)) << nf;
        }
      }
      mkc[j] = mk;
    }

    // S = Q @ K^T : 16 q-rows x 64 k-cols (K from LDS)
    f32x4 sacc[4];
#pragma unroll
    for (int nf = 0; nf < 4; ++nf) sacc[nf] = zero4;
#pragma unroll
    for (int kk = 0; kk < 2; ++kk) {
      bf16x8 kf[4];
#pragma unroll
      for (int nf = 0; nf < 4; ++nf) {
        int row = nf * 16 + l15;
        int off = (kk * 64 + lg * 16) ^ ((row & 7) << 4);
        kf[nf] = *(const bf16x8*)((const char*)lK[cur] + row * 128 + off);
      }
#pragma unroll
      for (int nf = 0; nf < 4; ++nf)
        sacc[nf] = __builtin_amdgcn_mfma_f32_16x16x32_bf16(qf[kk], kf[nf],
                                                           sacc[nf], 0, 0, 0);
    }

    // scale*aw, mask, online softmax; P -> per-wave LDS tile
    float alpha[4];
#pragma unroll
    for (int j = 0; j < 4; ++j) {
      float mx = -1e30f;
#pragma unroll
      for (int nf = 0; nf < 4; ++nf) {
        float s = sacc[nf][j] * scale * awc[j][nf];
        s = ((mkc[j] >> nf) & 1u) ? -1e30f : s;
        sacc[nf][j] = s;
        mx = fmaxf(mx, s);
      }
      mx = fmaxf(mx, __shfl_xor(mx, 1));
      mx = fmaxf(mx, __shfl_xor(mx, 2));
      mx = fmaxf(mx, __shfl_xor(mx, 4));
      mx = fmaxf(mx, __shfl_xor(mx, 8));
      float mnew = fmaxf(mrun[j], mx);
      float al = __expf(mrun[j] - mnew);
      mrun[j] = mnew;
      float psum = 0.f;
      const int prow = lg * 4 + j;
      const int swp = (prow & 7) << 4;
#pragma unroll
      for (int nf = 0; nf < 4; ++nf) {
        float s = sacc[nf][j];
        float p = (s <= -1e29f) ? 0.f : __expf(s - mnew);
        psum += p;
        *(unsigned short*)((char*)lP[wave] + prow * 128 +
                           (((nf * 16 + l15) * 2) ^ swp)) = f2bf(p);
      }
      psum += __shfl_xor(psum, 1);
      psum += __shfl_xor(psum, 2);
      psum += __shfl_xor(psum, 4);
      psum += __shfl_xor(psum, 8);
      lrun[j] = lrun[j] * al + psum;
      alpha[j] = al;
    }
#pragma unroll
    for (int df = 0; df < 4; ++df)
#pragma unroll
      for (int j = 0; j < 4; ++j) oacc[df][j] *= alpha[j];

    // O += P @ V  (V direct from global, per-kk2 batch: 16 transient VGPRs)
#pragma unroll
    for (int kk2 = 0; kk2 < 2; ++kk2) {
      bf16x8 pf;
      {
        int off = (kk2 * 64 + lg * 16) ^ ((l15 & 7) << 4);
        pf = *(const bf16x8*)((const char*)lP[wave] + l15 * 128 + off);
      }
#pragma unroll
      for (int df = 0; df < 4; ++df) {
        bf16x8 vf = *(const bf16x8*)&vp[(size_t)(df * 16 + l15) * 1024 +
                                        kt * 64 + kk2 * 32 + lg * 8];
        oacc[df] = __builtin_amdgcn_mfma_f32_16x16x32_bf16(pf, vf,
                                                           oacc[df], 0, 0, 0);
      }
    }
    __syncthreads();  // next K tile staged; all lK[cur]/lP reads done
  }

  // epilogue: write bf16 partial O + fp32 (m,l)
#pragma unroll
  for (int j = 0; j < 4; ++j) {
    const int r = qrow0 + lg * 4 + j;
    const size_t row = (size_t)bh * 1024 + r;
    if (l15 == 0) stats[(size_t)half * 65536 + row] = make_float2(mrun[j], lrun[j]);
#pragma unroll
    for (int df = 0; df < 4; ++df)
      opart[((size_t)half * 65536 + row) * 64 + df * 16 + l15] =
          f2bf(oacc[df][j]);
  }
}

// ---------------- flash-merge of the two kt-halves ----------------
__global__ __launch_bounds__(256) void merge_kernel(
    const unsigned short* __restrict__ opart, const float2* __restrict__ stats,
    unsigned short* __restrict__ attnout) {
  const int idx = blockIdx.x * 256 + threadIdx.x;  // 524288 threads
  const int row = idx >> 3, seg = idx & 7;
  float2 s0 = stats[row], s1 = stats[65536 + row];
  float M = fmaxf(s0.x, s1.x);
  float a0 = __expf(s0.x - M), a1 = __expf(s1.x - M);
  float inv = 1.0f / (s0.y * a0 + s1.y * a1);
  bf16x8 O0 = *(const bf16x8*)&opart[(size_t)row * 64 + seg * 8];
  bf16x8 O1 = *(const bf16x8*)&opart[(size_t)(65536 + row) * 64 + seg * 8];
  const int bh = row >> 10, qq = row & 1023;
  const int b = bh >> 4, h = bh & 15;
  bf16x8 o;
#pragma unroll
  for (int j = 0; j < 8; ++j)
    o[j] = (short)f2bf((bf2f((unsigned short)O0[j]) * a0 +
                        bf2f((unsigned short)O1[j]) * a1) * inv);
  *(bf16x8*)&attnout[(size_t)(b * 1024 + qq) * 1024 + h * 64 + seg * 8] = o;
}

extern "C" void kernel_launch(void* const* d_in, const int* in_sizes, int n_in,
                              void* d_out, int out_size, void* d_ws, size_t ws_size,
                              hipStream_t stream) {
  const float* queries = (const float*)d_in[0];
  const float* keys1 = (const float*)d_in[1];
  const float* keys2 = (const float*)d_in[2];
  const float* values = (const float*)d_in[3];
  const float* aw = (const float*)d_in[4];
  const void* mask = d_in[5];
  const float* Wq = (const float*)d_in[6];
  const float* bq = (const float*)d_in[7];
  const float* Wk1 = (const float*)d_in[8];
  const float* bk1 = (const float*)d_in[9];
  const float* Wk2 = (const float*)d_in[10];
  const float* bk2 = (const float*)d_in[11];
  const float* Wv = (const float*)d_in[12];
  const float* bv = (const float*)d_in[13];
  const float* Wo = (const float*)d_in[14];
  const float* bo = (const float*)d_in[15];

  char* ws = (char*)d_ws;
  unsigned short* qbf = (unsigned short*)(ws + (0ull << 20));
  unsigned short* khat = (unsigned short*)(ws + (8ull << 20));
  unsigned short* vTb = (unsigned short*)(ws + (16ull << 20));
  unsigned short* attno = (unsigned short*)(ws + (24ull << 20));
  unsigned short* WT = (unsigned short*)(ws + (32ull << 20));
  unsigned short* WoT = WT;                   // z=0 at 32 MiB (survives attn)
  unsigned short* WqT = WT + 1 * 1048576;     // 34 MiB
  unsigned short* Wk1T = WT + 2 * 1048576;    // 36
  unsigned short* Wk2T = WT + 3 * 1048576;    // 38
  unsigned short* WvT = WT + 4 * 1048576;     // 40
  unsigned short* opart = (unsigned short*)(ws + (34ull << 20));  // 16 MiB
  float2* stats = (float2*)(ws + (50ull << 20));                  // 1 MiB

  transpose5_kernel<<<dim3(32, 32, 5), 256, 0, stream>>>(
      W5{Wo, Wq, Wk1, Wk2, Wv}, WT);

  const dim3 gg(64, 16);  // M/64, N/64
  gemm64_kernel<0><<<gg, 256, 0, stream>>>(queries, WqT, nullptr, nullptr,
                                           bq, nullptr, qbf, 4096, 1024, 1024, 0);
  gemm64_kernel<0><<<gg, 256, 0, stream>>>(keys1, Wk1T, keys2, Wk2T,
                                           bk1, bk2, khat, 4096, 1024, 1024, 0);
  gemm64_kernel<0><<<gg, 256, 0, stream>>>(values, WvT, nullptr, nullptr,
                                           bv, nullptr, vTb, 4096, 1024, 1024, 1);

  attn_kernel<<<2048, 256, 0, stream>>>(qbf, khat, vTb, aw, mask, opart, stats);
  merge_kernel<<<2048, 256, 0, stream>>>(opart, stats, attno);

  gemm64_kernel<1><<<gg, 256, 0, stream>>>(attno, WoT, nullptr, nullptr,
                                           bo, nullptr, d_out, 4096, 1024, 1024, 2);
}

// Round 11
// 308.330 us; speedup vs baseline: 2.1973x; 1.6223x over previous
//
#include <hip/hip_runtime.h>

// Dual-key attention, bf16 MFMA pipeline. ws_size >= 51 MiB.
// ws layout (MiB offsets):
//   0: qbf   [b][h][1024][64] bf16   (8 MiB)
//   8: khat  [b][h][1024][64] bf16   (8)
//  16: vT    [b][h][64][1024] bf16   (8)
//  24: attno [b*1024+n][h*64+d] bf16 (8)
//  32: WoT bf16 (2)
//  34: WqT, 36: Wk1T, 38: Wk2T, 40: WvT (2 each; dead after projections ->
//       overwritten by attn partials:)
//  34: Opart[2][bh*1024+q][64] bf16 (16 MiB total)
//  50: stats[2][bh*1024+q] float2   (1 MiB)

typedef short bf16x8 __attribute__((ext_vector_type(8)));
typedef float f32x4 __attribute__((ext_vector_type(4)));

__device__ __forceinline__ unsigned short f2bf(float f) {
  unsigned int u = __float_as_uint(f);
  return (unsigned short)((u + 0x7FFFu + ((u >> 16) & 1u)) >> 16);
}

__device__ __forceinline__ float bf2f(unsigned short u) {
  return __uint_as_float((unsigned)u << 16);
}

__device__ __forceinline__ bf16x8 pack8(float4 a, float4 b) {
  bf16x8 r;
  r[0] = (short)f2bf(a.x); r[1] = (short)f2bf(a.y);
  r[2] = (short)f2bf(a.z); r[3] = (short)f2bf(a.w);
  r[4] = (short)f2bf(b.x); r[5] = (short)f2bf(b.y);
  r[6] = (short)f2bf(b.z); r[7] = (short)f2bf(b.w);
  return r;
}

__device__ __forceinline__ void gload_lds16(const void* g, void* l) {
  __builtin_amdgcn_global_load_lds(
      (const __attribute__((address_space(1))) unsigned int*)g,
      (__attribute__((address_space(3))) unsigned int*)l, 16, 0, 0);
}

// ---------------- batched W [1024][1024] fp32 -> W^T bf16 (5 weights) -------
struct W5 { const float *w0, *w1, *w2, *w3, *w4; };

__global__ __launch_bounds__(256) void transpose5_kernel(W5 w, unsigned short* out) {
  __shared__ float tile[32][33];
  const int z = blockIdx.z;
  const float* in = (z == 0) ? w.w0 : (z == 1) ? w.w1 : (z == 2) ? w.w2
                    : (z == 3) ? w.w3 : w.w4;
  unsigned short* o = out + (size_t)z * (1024 * 1024);
  const int x = threadIdx.x & 31;
  const int y0 = (threadIdx.x >> 5) << 2;
  const int r0 = blockIdx.y * 32, c0 = blockIdx.x * 32;
#pragma unroll
  for (int i = 0; i < 4; ++i)
    tile[y0 + i][x] = in[(size_t)(r0 + y0 + i) * 1024 + c0 + x];
  __syncthreads();
#pragma unroll
  for (int i = 0; i < 4; ++i) {
    int c = y0 + i;
    o[(size_t)(c0 + c) * 1024 + r0 + x] = f2bf(tile[x][c]);
  }
}

// ---------------- 64x64-tile, BK=64 MFMA GEMM: C = A1@B1^T (+A2@B2^T) + bias
template <int AMODE>
__global__ __launch_bounds__(256, 4) void gemm64_kernel(
    const void* A1v, const unsigned short* __restrict__ B1,
    const void* A2v, const unsigned short* __restrict__ B2,
    const float* __restrict__ bias1, const float* __restrict__ bias2,
    void* __restrict__ outp, int M, int N, int K, int omode) {
  __shared__ unsigned short lA[2][64 * 64];
  __shared__ unsigned short lB[2][64 * 64];
  const int tid = threadIdx.x;
  const int lane = tid & 63, wave = tid >> 6;
  const int l15 = lane & 15, lg = lane >> 4;
  const int m0 = blockIdx.x * 64, n0 = blockIdx.y * 64;
  const int wr = wave >> 1, wc = wave & 1;
  const int arow = tid >> 2;
  const int acb = (tid & 3) * 32;

  f32x4 zero4 = {0.f, 0.f, 0.f, 0.f};
  f32x4 acc[2][2];
#pragma unroll
  for (int i = 0; i < 2; ++i)
#pragma unroll
    for (int j = 0; j < 2; ++j) acc[i][j] = zero4;

  const int ksteps = K >> 6;
  const int npair = (A2v != nullptr) ? 2 : 1;
  const int nsteps = npair * ksteps;

  {
#pragma unroll
    for (int rep = 0; rep < 2; ++rep) {
      int c = rep * 256 + tid;
      int row = c >> 3;
      int off = ((c & 7) * 16) ^ ((row & 7) << 4);
      gload_lds16(&B1[(size_t)(n0 + row) * K + (off >> 1)],
                  (char*)lB[0] + rep * 4096 + wave * 1024);
      if (AMODE == 1)
        gload_lds16(&((const unsigned short*)A1v)[(size_t)(m0 + row) * K + (off >> 1)],
                    (char*)lA[0] + rep * 4096 + wave * 1024);
    }
    if (AMODE == 0) {
      const float* A = (const float*)A1v;
      const int ce = acb >> 1;
      float4 a0 = *(const float4*)&A[(size_t)(m0 + arow) * K + ce];
      float4 a1 = *(const float4*)&A[(size_t)(m0 + arow) * K + ce + 4];
      float4 a2 = *(const float4*)&A[(size_t)(m0 + arow) * K + ce + 8];
      float4 a3 = *(const float4*)&A[(size_t)(m0 + arow) * K + ce + 12];
      int sw = (arow & 7) << 4;
      *(bf16x8*)((char*)lA[0] + arow * 128 + (acb ^ sw)) = pack8(a0, a1);
      *(bf16x8*)((char*)lA[0] + arow * 128 + ((acb + 16) ^ sw)) = pack8(a2, a3);
    }
  }
  __syncthreads();

  for (int s = 0; s < nsteps; ++s) {
    const int cur = s & 1, nxt = cur ^ 1;
    const bool hn = (s + 1 < nsteps);
    float4 a0, a1, a2, a3;
    if (hn) {
      const int s1 = s + 1;
      const int p1 = (s1 >= ksteps) ? 1 : 0;
      const int k1 = (s1 - p1 * ksteps) * 64;
      const unsigned short* B = p1 ? B2 : B1;
#pragma unroll
      for (int rep = 0; rep < 2; ++rep) {
        int c = rep * 256 + tid;
        int row = c >> 3;
        int off = ((c & 7) * 16) ^ ((row & 7) << 4);
        gload_lds16(&B[(size_t)(n0 + row) * K + k1 + (off >> 1)],
                    (char*)lB[nxt] + rep * 4096 + wave * 1024);
        if (AMODE == 1)
          gload_lds16(&((const unsigned short*)(p1 ? A2v : A1v))
                          [(size_t)(m0 + row) * K + k1 + (off >> 1)],
                      (char*)lA[nxt] + rep * 4096 + wave * 1024);
      }
      if (AMODE == 0) {
        const float* A = (const float*)(p1 ? A2v : A1v);
        const int ce = k1 + (acb >> 1);
        a0 = *(const float4*)&A[(size_t)(m0 + arow) * K + ce];
        a1 = *(const float4*)&A[(size_t)(m0 + arow) * K + ce + 4];
        a2 = *(const float4*)&A[(size_t)(m0 + arow) * K + ce + 8];
        a3 = *(const float4*)&A[(size_t)(m0 + arow) * K + ce + 12];
      }
    }
    bf16x8 af[2][2], bfr[2][2];
#pragma unroll
    for (int mf = 0; mf < 2; ++mf) {
      int row = wr * 32 + mf * 16 + l15;
      int sw = (row & 7) << 4;
#pragma unroll
      for (int kk = 0; kk < 2; ++kk)
        af[mf][kk] = *(const bf16x8*)((const char*)lA[cur] + row * 128 +
                                      ((kk * 64 + lg * 16) ^ sw));
    }
#pragma unroll
    for (int nf = 0; nf < 2; ++nf) {
      int row = wc * 32 + nf * 16 + l15;
      int sw = (row & 7) << 4;
#pragma unroll
      for (int kk = 0; kk < 2; ++kk)
        bfr[nf][kk] = *(const bf16x8*)((const char*)lB[cur] + row * 128 +
                                       ((kk * 64 + lg * 16) ^ sw));
    }
#pragma unroll
    for (int kk = 0; kk < 2; ++kk)
#pragma unroll
      for (int mf = 0; mf < 2; ++mf)
#pragma unroll
        for (int nf = 0; nf < 2; ++nf)
          acc[mf][nf] = __builtin_amdgcn_mfma_f32_16x16x32_bf16(
              af[mf][kk], bfr[nf][kk], acc[mf][nf], 0, 0, 0);
    if (AMODE == 0 && hn) {
      int sw = (arow & 7) << 4;
      *(bf16x8*)((char*)lA[nxt] + arow * 128 + (acb ^ sw)) = pack8(a0, a1);
      *(bf16x8*)((char*)lA[nxt] + arow * 128 + ((acb + 16) ^ sw)) = pack8(a2, a3);
    }
    __syncthreads();
  }

  unsigned short* outb = (unsigned short*)outp;
  float* outf = (float*)outp;
#pragma unroll
  for (int mf = 0; mf < 2; ++mf) {
#pragma unroll
    for (int nf = 0; nf < 2; ++nf) {
      int cg = n0 + wc * 32 + nf * 16 + l15;
      float badd = (bias1 ? bias1[cg] : 0.f) + (bias2 ? bias2[cg] : 0.f);
#pragma unroll
      for (int j = 0; j < 4; ++j) {
        int r = m0 + wr * 32 + mf * 16 + lg * 4 + j;
        float v = acc[mf][nf][j] + badd;
        if (omode == 2) {
          outf[(size_t)r * N + cg] = v;
        } else {
          int bb = r >> 10, nn = r & 1023;
          int hh = cg >> 6, dd = cg & 63;
          if (omode == 0)
            outb[(((size_t)bb * 16 + hh) * 1024 + nn) * 64 + dd] = f2bf(v);
          else
            outb[(((size_t)bb * 16 + hh) * 64 + dd) * 1024 + nn] = f2bf(v);
        }
      }
    }
  }
}

// ---------------- fused dual-key attention (r3 loop, kt-split x2) ----------
// 2048 blocks: swb = bh(64) x half(2) x qt16(16). 4 waves x 16 q-rows cover
// a 64-row q-group; each block iterates 8 of 16 K-tiles (KVBLK=64). K staged
// dbuf via global_load_lds (16KB LDS); V direct from global (L2-resident via
// XCD swizzle); per-wave P tile (8KB). LDS 24KB. (256,4): budget 128, loop
// compiles ~64 VGPR -> runtime 6 blocks/CU (LDS-capped) without spill.
// aw/mask at POINT OF USE (r3 pattern) - hoisting them spilled (r10).
__global__ __launch_bounds__(256, 4) void attn_kernel(
    const unsigned short* __restrict__ q, const unsigned short* __restrict__ kh,
    const unsigned short* __restrict__ vT, const float* __restrict__ aw,
    const void* __restrict__ msk, unsigned short* __restrict__ opart,
    float2* __restrict__ stats) {
  __shared__ unsigned short lK[2][64 * 64];  // [k][d] 128B rows, XOR-swizzled
  __shared__ unsigned short lP[4][16 * 64];  // per-wave P tile, swizzled

  const int tid = threadIdx.x, lane = tid & 63, wave = tid >> 6;
  const int l15 = lane & 15, lg = lane >> 4;
  // XCD swizzle (2048 % 8 == 0): each XCD gets 256 consecutive swb = 8 bh ->
  // K/V working set 8 x 256 KB = 2 MB fits the 4 MB per-XCD L2.
  const int bid = blockIdx.x;
  const int swb = (bid & 7) * 256 + (bid >> 3);
  const int bh = swb >> 5;            // [0,64)
  const int half = (swb >> 4) & 1;    // [0,2)
  const int qt16 = swb & 15;          // [0,16)
  const int qrow0 = qt16 * 64 + wave * 16;

  // mask dtype detection (wave-uniform): i32 0/1 words are always <=1
  unsigned w0 = ((const unsigned*)msk)[lane];
  const bool mbyte = (__ballot(w0 > 1u) != 0ull);
  const unsigned char* mp8 = (const unsigned char*)msk + (size_t)bh * 1048576;
  const int* mpi = (const int*)msk + (size_t)bh * 1048576;

  const unsigned short* qp = q + (size_t)bh * 65536;
  const unsigned short* kp = kh + (size_t)bh * 65536;
  const unsigned short* vp = vT + (size_t)bh * 65536;
  const float* awp = aw + (size_t)bh * 1048576;

  bf16x8 qf[2];
#pragma unroll
  for (int kk = 0; kk < 2; ++kk)
    qf[kk] = *(const bf16x8*)&qp[(qrow0 + l15) * 64 + kk * 32 + lg * 8];

  f32x4 zero4 = {0.f, 0.f, 0.f, 0.f};
  f32x4 oacc[4];
  float mrun[4], lrun[4];
#pragma unroll
  for (int x = 0; x < 4; ++x) {
    oacc[x] = zero4;
    mrun[x] = -1e30f;
    lrun[x] = 0.f;
  }

  const float scale = 0.08838834764831845f;  // 1/sqrt(128)
  const int kt0 = half * 8;

  // prologue: stage tile kt0 into buf 0
#pragma unroll
  for (int rep = 0; rep < 2; ++rep) {
    int c = rep * 256 + tid;
    int row = c >> 3;
    int off = ((c & 7) * 16) ^ ((row & 7) << 4);
    gload_lds16(&kp[(size_t)(kt0 * 64 + row) * 64 + (off >> 1)],
                (char*)lK[0] + rep * 4096 + wave * 1024);
  }
  __syncthreads();

  for (int it = 0; it < 8; ++it) {
    const int kt = kt0 + it;
    const int cur = it & 1, nxt = cur ^ 1;
    if (it < 7) {
#pragma unroll
      for (int rep = 0; rep < 2; ++rep) {
        int c = rep * 256 + tid;
        int row = c >> 3;
        int off = ((c & 7) * 16) ^ ((row & 7) << 4);
        gload_lds16(&kp[(size_t)((kt + 1) * 64 + row) * 64 + (off >> 1)],
                    (char*)lK[nxt] + rep * 4096 + wave * 1024);
      }
    }

    // S = Q @ K^T : 16 q-rows x 64 k-cols (K from LDS)
    f32x4 sacc[4];
#pragma unroll
    for (int nf = 0; nf < 4; ++nf) sacc[nf] = zero4;
#pragma unroll
    for (int kk = 0; kk < 2; ++kk) {
      bf16x8 kf[4];
#pragma unroll
      for (int nf = 0; nf < 4; ++nf) {
        int row = nf * 16 + l15;
        int off = (kk * 64 + lg * 16) ^ ((row & 7) << 4);
        kf[nf] = *(const bf16x8*)((const char*)lK[cur] + row * 128 + off);
      }
#pragma unroll
      for (int nf = 0; nf < 4; ++nf)
        sacc[nf] = __builtin_amdgcn_mfma_f32_16x16x32_bf16(qf[kk], kf[nf],
                                                           sacc[nf], 0, 0, 0);
    }

    // scale*aw, mask, online softmax (aw/mask at point of use); P -> LDS
    float alpha[4];
#pragma unroll
    for (int j = 0; j < 4; ++j) {
      const int r = qrow0 + lg * 4 + j;
      const float* awrow = awp + (size_t)r * 1024 + kt * 64;
      const size_t mb = (size_t)r * 1024 + kt * 64;
      int mvv[4];
      if (mbyte) {
#pragma unroll
        for (int nf = 0; nf < 4; ++nf) mvv[nf] = mp8[mb + nf * 16 + l15];
      } else {
#pragma unroll
        for (int nf = 0; nf < 4; ++nf) mvv[nf] = (mpi[mb + nf * 16 + l15] != 0);
      }
      float mx = -1e30f;
#pragma unroll
      for (int nf = 0; nf < 4; ++nf) {
        float s = sacc[nf][j] * scale * awrow[nf * 16 + l15];
        s = mvv[nf] ? -1e30f : s;
        sacc[nf][j] = s;
        mx = fmaxf(mx, s);
      }
      mx = fmaxf(mx, __shfl_xor(mx, 1));
      mx = fmaxf(mx, __shfl_xor(mx, 2));
      mx = fmaxf(mx, __shfl_xor(mx, 4));
      mx = fmaxf(mx, __shfl_xor(mx, 8));
      float mnew = fmaxf(mrun[j], mx);
      float al = __expf(mrun[j] - mnew);
      mrun[j] = mnew;
      float psum = 0.f;
      const int prow = lg * 4 + j;
      const int swp = (prow & 7) << 4;
#pragma unroll
      for (int nf = 0; nf < 4; ++nf) {
        float s = sacc[nf][j];
        float p = (s <= -1e29f) ? 0.f : __expf(s - mnew);
        psum += p;
        *(unsigned short*)((char*)lP[wave] + prow * 128 +
                           (((nf * 16 + l15) * 2) ^ swp)) = f2bf(p);
      }
      psum += __shfl_xor(psum, 1);
      psum += __shfl_xor(psum, 2);
      psum += __shfl_xor(psum, 4);
      psum += __shfl_xor(psum, 8);
      lrun[j] = lrun[j] * al + psum;
      alpha[j] = al;
    }
#pragma unroll
    for (int df = 0; df < 4; ++df)
#pragma unroll
      for (int j = 0; j < 4; ++j) oacc[df][j] *= alpha[j];

    // O += P @ V  (V direct from global, transient regs)
#pragma unroll
    for (int kk2 = 0; kk2 < 2; ++kk2) {
      bf16x8 pf;
      {
        int off = (kk2 * 64 + lg * 16) ^ ((l15 & 7) << 4);
        pf = *(const bf16x8*)((const char*)lP[wave] + l15 * 128 + off);
      }
#pragma unroll
      for (int df = 0; df < 4; ++df) {
        bf16x8 vf = *(const bf16x8*)&vp[(size_t)(df * 16 + l15) * 1024 +
                                        kt * 64 + kk2 * 32 + lg * 8];
        oacc[df] = __builtin_amdgcn_mfma_f32_16x16x32_bf16(pf, vf,
                                                           oacc[df], 0, 0, 0);
      }
    }
    __syncthreads();  // next K tile staged; all lK[cur]/lP reads done
  }

  // epilogue: write bf16 partial O + fp32 (m,l)
#pragma unroll
  for (int j = 0; j < 4; ++j) {
    const int r = qrow0 + lg * 4 + j;
    const size_t row = (size_t)bh * 1024 + r;
    if (l15 == 0) stats[(size_t)half * 65536 + row] = make_float2(mrun[j], lrun[j]);
#pragma unroll
    for (int df = 0; df < 4; ++df)
      opart[((size_t)half * 65536 + row) * 64 + df * 16 + l15] =
          f2bf(oacc[df][j]);
  }
}

// ---------------- flash-merge of the two kt-halves ----------------
__global__ __launch_bounds__(256) void merge_kernel(
    const unsigned short* __restrict__ opart, const float2* __restrict__ stats,
    unsigned short* __restrict__ attnout) {
  const int idx = blockIdx.x * 256 + threadIdx.x;  // 524288 threads
  const int row = idx >> 3, seg = idx & 7;
  float2 s0 = stats[row], s1 = stats[65536 + row];
  float M = fmaxf(s0.x, s1.x);
  float a0 = __expf(s0.x - M), a1 = __expf(s1.x - M);
  float inv = 1.0f / (s0.y * a0 + s1.y * a1);
  bf16x8 O0 = *(const bf16x8*)&opart[(size_t)row * 64 + seg * 8];
  bf16x8 O1 = *(const bf16x8*)&opart[(size_t)(65536 + row) * 64 + seg * 8];
  const int bh = row >> 10, qq = row & 1023;
  const int b = bh >> 4, h = bh & 15;
  bf16x8 o;
#pragma unroll
  for (int j = 0; j < 8; ++j)
    o[j] = (short)f2bf((bf2f((unsigned short)O0[j]) * a0 +
                        bf2f((unsigned short)O1[j]) * a1) * inv);
  *(bf16x8*)&attnout[(size_t)(b * 1024 + qq) * 1024 + h * 64 + seg * 8] = o;
}

extern "C" void kernel_launch(void* const* d_in, const int* in_sizes, int n_in,
                              void* d_out, int out_size, void* d_ws, size_t ws_size,
                              hipStream_t stream) {
  const float* queries = (const float*)d_in[0];
  const float* keys1 = (const float*)d_in[1];
  const float* keys2 = (const float*)d_in[2];
  const float* values = (const float*)d_in[3];
  const float* aw = (const float*)d_in[4];
  const void* mask = d_in[5];
  const float* Wq = (const float*)d_in[6];
  const float* bq = (const float*)d_in[7];
  const float* Wk1 = (const float*)d_in[8];
  const float* bk1 = (const float*)d_in[9];
  const float* Wk2 = (const float*)d_in[10];
  const float* bk2 = (const float*)d_in[11];
  const float* Wv = (const float*)d_in[12];
  const float* bv = (const float*)d_in[13];
  const float* Wo = (const float*)d_in[14];
  const float* bo = (const float*)d_in[15];

  char* ws = (char*)d_ws;
  unsigned short* qbf = (unsigned short*)(ws + (0ull << 20));
  unsigned short* khat = (unsigned short*)(ws + (8ull << 20));
  unsigned short* vTb = (unsigned short*)(ws + (16ull << 20));
  unsigned short* attno = (unsigned short*)(ws + (24ull << 20));
  unsigned short* WT = (unsigned short*)(ws + (32ull << 20));
  unsigned short* WoT = WT;                   // z=0 at 32 MiB (survives attn)
  unsigned short* WqT = WT + 1 * 1048576;     // 34 MiB
  unsigned short* Wk1T = WT + 2 * 1048576;    // 36
  unsigned short* Wk2T = WT + 3 * 1048576;    // 38
  unsigned short* WvT = WT + 4 * 1048576;     // 40
  unsigned short* opart = (unsigned short*)(ws + (34ull << 20));  // 16 MiB
  float2* stats = (float2*)(ws + (50ull << 20));                  // 1 MiB

  transpose5_kernel<<<dim3(32, 32, 5), 256, 0, stream>>>(
      W5{Wo, Wq, Wk1, Wk2, Wv}, WT);

  const dim3 gg(64, 16);  // M/64, N/64
  gemm64_kernel<0><<<gg, 256, 0, stream>>>(queries, WqT, nullptr, nullptr,
                                           bq, nullptr, qbf, 4096, 1024, 1024, 0);
  gemm64_kernel<0><<<gg, 256, 0, stream>>>(keys1, Wk1T, keys2, Wk2T,
                                           bk1, bk2, khat, 4096, 1024, 1024, 0);
  gemm64_kernel<0><<<gg, 256, 0, stream>>>(values, WvT, nullptr, nullptr,
                                           bv, nullptr, vTb, 4096, 1024, 1024, 1);

  attn_kernel<<<2048, 256, 0, stream>>>(qbf, khat, vTb, aw, mask, opart, stats);
  merge_kernel<<<2048, 256, 0, stream>>>(opart, stats, attno);

  gemm64_kernel<1><<<gg, 256, 0, stream>>>(attno, WoT, nullptr, nullptr,
                                           bo, nullptr, d_out, 4096, 1024, 1024, 2);
}

// Round 12
// 278.632 us; speedup vs baseline: 2.4315x; 1.1066x over previous
//
#include <hip/hip_runtime.h>

// Dual-key attention, bf16 MFMA pipeline. ws_size >= 51 MiB.
// ws layout (MiB offsets):
//   0: qbf   [b][h][1024][64] bf16   (8 MiB)
//   8: khat  [b][h][1024][64] bf16   (8)
//  16: vT    [b][h][64][1024] bf16   (8)
//  24: attno [b*1024+n][h*64+d] bf16 (8)
//  32: WoT bf16 (2)
//  34: WqT, 36: Wk1T, 38: Wk2T, 40: WvT (2 each; dead after projections ->
//       overwritten by attn partials:)
//  34: Opart[2][bh*1024+q][64] bf16 (16 MiB total)
//  50: stats[2][bh*1024+q] float2   (1 MiB)

typedef short bf16x8 __attribute__((ext_vector_type(8)));
typedef float f32x4 __attribute__((ext_vector_type(4)));

__device__ __forceinline__ unsigned short f2bf(float f) {
  unsigned int u = __float_as_uint(f);
  return (unsigned short)((u + 0x7FFFu + ((u >> 16) & 1u)) >> 16);
}

__device__ __forceinline__ float bf2f(unsigned short u) {
  return __uint_as_float((unsigned)u << 16);
}

__device__ __forceinline__ bf16x8 pack8(float4 a, float4 b) {
  bf16x8 r;
  r[0] = (short)f2bf(a.x); r[1] = (short)f2bf(a.y);
  r[2] = (short)f2bf(a.z); r[3] = (short)f2bf(a.w);
  r[4] = (short)f2bf(b.x); r[5] = (short)f2bf(b.y);
  r[6] = (short)f2bf(b.z); r[7] = (short)f2bf(b.w);
  return r;
}

__device__ __forceinline__ void gload_lds16(const void* g, void* l) {
  __builtin_amdgcn_global_load_lds(
      (const __attribute__((address_space(1))) unsigned int*)g,
      (__attribute__((address_space(3))) unsigned int*)l, 16, 0, 0);
}

// ---------------- batched W [1024][1024] fp32 -> W^T bf16 (5 weights) -------
struct W5 { const float *w0, *w1, *w2, *w3, *w4; };

__global__ __launch_bounds__(256) void transpose5_kernel(W5 w, unsigned short* out) {
  __shared__ float tile[32][33];
  const int z = blockIdx.z;
  const float* in = (z == 0) ? w.w0 : (z == 1) ? w.w1 : (z == 2) ? w.w2
                    : (z == 3) ? w.w3 : w.w4;
  unsigned short* o = out + (size_t)z * (1024 * 1024);
  const int x = threadIdx.x & 31;
  const int y0 = (threadIdx.x >> 5) << 2;
  const int r0 = blockIdx.y * 32, c0 = blockIdx.x * 32;
#pragma unroll
  for (int i = 0; i < 4; ++i)
    tile[y0 + i][x] = in[(size_t)(r0 + y0 + i) * 1024 + c0 + x];
  __syncthreads();
#pragma unroll
  for (int i = 0; i < 4; ++i) {
    int c = y0 + i;
    o[(size_t)(c0 + c) * 1024 + r0 + x] = f2bf(tile[x][c]);
  }
}

// ---------------- 64x64-tile, BK=64 MFMA GEMM: C = A1@B1^T (+A2@B2^T) + bias
template <int AMODE>
__global__ __launch_bounds__(256, 4) void gemm64_kernel(
    const void* A1v, const unsigned short* __restrict__ B1,
    const void* A2v, const unsigned short* __restrict__ B2,
    const float* __restrict__ bias1, const float* __restrict__ bias2,
    void* __restrict__ outp, int M, int N, int K, int omode) {
  __shared__ unsigned short lA[2][64 * 64];
  __shared__ unsigned short lB[2][64 * 64];
  const int tid = threadIdx.x;
  const int lane = tid & 63, wave = tid >> 6;
  const int l15 = lane & 15, lg = lane >> 4;
  const int m0 = blockIdx.x * 64, n0 = blockIdx.y * 64;
  const int wr = wave >> 1, wc = wave & 1;
  const int arow = tid >> 2;
  const int acb = (tid & 3) * 32;

  f32x4 zero4 = {0.f, 0.f, 0.f, 0.f};
  f32x4 acc[2][2];
#pragma unroll
  for (int i = 0; i < 2; ++i)
#pragma unroll
    for (int j = 0; j < 2; ++j) acc[i][j] = zero4;

  const int ksteps = K >> 6;
  const int npair = (A2v != nullptr) ? 2 : 1;
  const int nsteps = npair * ksteps;

  {
#pragma unroll
    for (int rep = 0; rep < 2; ++rep) {
      int c = rep * 256 + tid;
      int row = c >> 3;
      int off = ((c & 7) * 16) ^ ((row & 7) << 4);
      gload_lds16(&B1[(size_t)(n0 + row) * K + (off >> 1)],
                  (char*)lB[0] + rep * 4096 + wave * 1024);
      if (AMODE == 1)
        gload_lds16(&((const unsigned short*)A1v)[(size_t)(m0 + row) * K + (off >> 1)],
                    (char*)lA[0] + rep * 4096 + wave * 1024);
    }
    if (AMODE == 0) {
      const float* A = (const float*)A1v;
      const int ce = acb >> 1;
      float4 a0 = *(const float4*)&A[(size_t)(m0 + arow) * K + ce];
      float4 a1 = *(const float4*)&A[(size_t)(m0 + arow) * K + ce + 4];
      float4 a2 = *(const float4*)&A[(size_t)(m0 + arow) * K + ce + 8];
      float4 a3 = *(const float4*)&A[(size_t)(m0 + arow) * K + ce + 12];
      int sw = (arow & 7) << 4;
      *(bf16x8*)((char*)lA[0] + arow * 128 + (acb ^ sw)) = pack8(a0, a1);
      *(bf16x8*)((char*)lA[0] + arow * 128 + ((acb + 16) ^ sw)) = pack8(a2, a3);
    }
  }
  __syncthreads();

  for (int s = 0; s < nsteps; ++s) {
    const int cur = s & 1, nxt = cur ^ 1;
    const bool hn = (s + 1 < nsteps);
    float4 a0, a1, a2, a3;
    if (hn) {
      const int s1 = s + 1;
      const int p1 = (s1 >= ksteps) ? 1 : 0;
      const int k1 = (s1 - p1 * ksteps) * 64;
      const unsigned short* B = p1 ? B2 : B1;
#pragma unroll
      for (int rep = 0; rep < 2; ++rep) {
        int c = rep * 256 + tid;
        int row = c >> 3;
        int off = ((c & 7) * 16) ^ ((row & 7) << 4);
        gload_lds16(&B[(size_t)(n0 + row) * K + k1 + (off >> 1)],
                    (char*)lB[nxt] + rep * 4096 + wave * 1024);
        if (AMODE == 1)
          gload_lds16(&((const unsigned short*)(p1 ? A2v : A1v))
                          [(size_t)(m0 + row) * K + k1 + (off >> 1)],
                      (char*)lA[nxt] + rep * 4096 + wave * 1024);
      }
      if (AMODE == 0) {
        const float* A = (const float*)(p1 ? A2v : A1v);
        const int ce = k1 + (acb >> 1);
        a0 = *(const float4*)&A[(size_t)(m0 + arow) * K + ce];
        a1 = *(const float4*)&A[(size_t)(m0 + arow) * K + ce + 4];
        a2 = *(const float4*)&A[(size_t)(m0 + arow) * K + ce + 8];
        a3 = *(const float4*)&A[(size_t)(m0 + arow) * K + ce + 12];
      }
    }
    bf16x8 af[2][2], bfr[2][2];
#pragma unroll
    for (int mf = 0; mf < 2; ++mf) {
      int row = wr * 32 + mf * 16 + l15;
      int sw = (row & 7) << 4;
#pragma unroll
      for (int kk = 0; kk < 2; ++kk)
        af[mf][kk] = *(const bf16x8*)((const char*)lA[cur] + row * 128 +
                                      ((kk * 64 + lg * 16) ^ sw));
    }
#pragma unroll
    for (int nf = 0; nf < 2; ++nf) {
      int row = wc * 32 + nf * 16 + l15;
      int sw = (row & 7) << 4;
#pragma unroll
      for (int kk = 0; kk < 2; ++kk)
        bfr[nf][kk] = *(const bf16x8*)((const char*)lB[cur] + row * 128 +
                                       ((kk * 64 + lg * 16) ^ sw));
    }
#pragma unroll
    for (int kk = 0; kk < 2; ++kk)
#pragma unroll
      for (int mf = 0; mf < 2; ++mf)
#pragma unroll
        for (int nf = 0; nf < 2; ++nf)
          acc[mf][nf] = __builtin_amdgcn_mfma_f32_16x16x32_bf16(
              af[mf][kk], bfr[nf][kk], acc[mf][nf], 0, 0, 0);
    if (AMODE == 0 && hn) {
      int sw = (arow & 7) << 4;
      *(bf16x8*)((char*)lA[nxt] + arow * 128 + (acb ^ sw)) = pack8(a0, a1);
      *(bf16x8*)((char*)lA[nxt] + arow * 128 + ((acb + 16) ^ sw)) = pack8(a2, a3);
    }
    __syncthreads();
  }

  unsigned short* outb = (unsigned short*)outp;
  float* outf = (float*)outp;
#pragma unroll
  for (int mf = 0; mf < 2; ++mf) {
#pragma unroll
    for (int nf = 0; nf < 2; ++nf) {
      int cg = n0 + wc * 32 + nf * 16 + l15;
      float badd = (bias1 ? bias1[cg] : 0.f) + (bias2 ? bias2[cg] : 0.f);
#pragma unroll
      for (int j = 0; j < 4; ++j) {
        int r = m0 + wr * 32 + mf * 16 + lg * 4 + j;
        float v = acc[mf][nf][j] + badd;
        if (omode == 2) {
          outf[(size_t)r * N + cg] = v;
        } else {
          int bb = r >> 10, nn = r & 1023;
          int hh = cg >> 6, dd = cg & 63;
          if (omode == 0)
            outb[(((size_t)bb * 16 + hh) * 1024 + nn) * 64 + dd] = f2bf(v);
          else
            outb[(((size_t)bb * 16 + hh) * 64 + dd) * 1024 + nn] = f2bf(v);
        }
      }
    }
  }
}

// ---------------- fused dual-key attention ----------------
// r3 staged inner loop + kt-split x2 + tile-top aw/mask hoist.
// 2048 blocks: swb = bh(64) x half(2) x qt16(16). 4 waves x 16 q-rows cover
// a 64-row q-group; each block iterates 8 of 16 K-tiles (KVBLK=64). K AND V
// staged dbuf via global_load_lds (32KB LDS); per-wave P tile (8KB) -> 40KB,
// 4 blocks/CU (matches the ~4-wave/SIMD VGPR cap, so LDS is free). aw/mask
// for the whole tile hoisted to tile top (+20 VGPR, budget 128 at (256,4));
// ~400cy of QK ds_read+MFMA covers their HBM latency. Partial (m,l,O) out.
__global__ __launch_bounds__(256, 4) void attn_kernel(
    const unsigned short* __restrict__ q, const unsigned short* __restrict__ kh,
    const unsigned short* __restrict__ vT, const float* __restrict__ aw,
    const void* __restrict__ msk, unsigned short* __restrict__ opart,
    float2* __restrict__ stats) {
  __shared__ unsigned short lK[2][64 * 64];  // [k][d] 128B rows, XOR-swizzled
  __shared__ unsigned short lV[2][64 * 64];  // [d][k] 128B rows, XOR-swizzled
  __shared__ unsigned short lP[4][16 * 64];  // per-wave P tile, swizzled

  const int tid = threadIdx.x, lane = tid & 63, wave = tid >> 6;
  const int l15 = lane & 15, lg = lane >> 4;
  // XCD swizzle (2048 % 8 == 0): each XCD gets 256 consecutive swb = 8 bh ->
  // K/V working set 8 x 256 KB = 2 MB fits the 4 MB per-XCD L2.
  const int bid = blockIdx.x;
  const int swb = (bid & 7) * 256 + (bid >> 3);
  const int bh = swb >> 5;            // [0,64)
  const int half = (swb >> 4) & 1;    // [0,2)
  const int qt16 = swb & 15;          // [0,16)
  const int qrow0 = qt16 * 64 + wave * 16;

  // mask dtype detection (wave-uniform): i32 0/1 words are always <=1
  unsigned w0 = ((const unsigned*)msk)[lane];
  const bool mbyte = (__ballot(w0 > 1u) != 0ull);
  const unsigned char* mp8 = (const unsigned char*)msk + (size_t)bh * 1048576;
  const int* mpi = (const int*)msk + (size_t)bh * 1048576;

  const unsigned short* qp = q + (size_t)bh * 65536;
  const unsigned short* kp = kh + (size_t)bh * 65536;
  const unsigned short* vp = vT + (size_t)bh * 65536;
  const float* awp = aw + (size_t)bh * 1048576;

  bf16x8 qf[2];
#pragma unroll
  for (int kk = 0; kk < 2; ++kk)
    qf[kk] = *(const bf16x8*)&qp[(qrow0 + l15) * 64 + kk * 32 + lg * 8];

  f32x4 zero4 = {0.f, 0.f, 0.f, 0.f};
  f32x4 oacc[4];
  float mrun[4], lrun[4];
#pragma unroll
  for (int x = 0; x < 4; ++x) {
    oacc[x] = zero4;
    mrun[x] = -1e30f;
    lrun[x] = 0.f;
  }

  const float scale = 0.08838834764831845f;  // 1/sqrt(128)
  const int kt0 = half * 8;

  // prologue: stage tile kt0 (K and V) into buf 0
#pragma unroll
  for (int rep = 0; rep < 2; ++rep) {
    int c = rep * 256 + tid;
    int row = c >> 3;
    int off = ((c & 7) * 16) ^ ((row & 7) << 4);
    gload_lds16(&kp[(size_t)(kt0 * 64 + row) * 64 + (off >> 1)],
                (char*)lK[0] + rep * 4096 + wave * 1024);
    gload_lds16(&vp[(size_t)row * 1024 + kt0 * 64 + (off >> 1)],
                (char*)lV[0] + rep * 4096 + wave * 1024);
  }
  __syncthreads();

  for (int it = 0; it < 8; ++it) {
    const int kt = kt0 + it;
    const int cur = it & 1, nxt = cur ^ 1;
    if (it < 7) {
#pragma unroll
      for (int rep = 0; rep < 2; ++rep) {
        int c = rep * 256 + tid;
        int row = c >> 3;
        int off = ((c & 7) * 16) ^ ((row & 7) << 4);
        gload_lds16(&kp[(size_t)((kt + 1) * 64 + row) * 64 + (off >> 1)],
                    (char*)lK[nxt] + rep * 4096 + wave * 1024);
        gload_lds16(&vp[(size_t)row * 1024 + (kt + 1) * 64 + (off >> 1)],
                    (char*)lV[nxt] + rep * 4096 + wave * 1024);
      }
    }

    // aw/mask for the whole tile hoisted here: QK below covers their latency
    float awc[4][4];
    unsigned mkc[4];
#pragma unroll
    for (int j = 0; j < 4; ++j) {
      const int r = qrow0 + lg * 4 + j;
      const float* awrow = awp + (size_t)r * 1024 + kt * 64;
      const size_t mb = (size_t)r * 1024 + kt * 64;
      unsigned mk = 0;
      if (mbyte) {
#pragma unroll
        for (int nf = 0; nf < 4; ++nf) {
          awc[j][nf] = awrow[nf * 16 + l15];
          mk |= ((unsigned)mp8[mb + nf * 16 + l15] & 1u) << nf;
        }
      } else {
#pragma unroll
        for (int nf = 0; nf < 4; ++nf) {
          awc[j][nf] = awrow[nf * 16 + l15];
          mk |= ((unsigned)(mpi[mb + nf * 16 + l15] != 0)) << nf;
        }
      }
      mkc[j] = mk;
    }

    // S = Q @ K^T : 16 q-rows x 64 k-cols (K from LDS)
    f32x4 sacc[4];
#pragma unroll
    for (int nf = 0; nf < 4; ++nf) sacc[nf] = zero4;
#pragma unroll
    for (int kk = 0; kk < 2; ++kk) {
      bf16x8 kf[4];
#pragma unroll
      for (int nf = 0; nf < 4; ++nf) {
        int row = nf * 16 + l15;
        int off = (kk * 64 + lg * 16) ^ ((row & 7) << 4);
        kf[nf] = *(const bf16x8*)((const char*)lK[cur] + row * 128 + off);
      }
#pragma unroll
      for (int nf = 0; nf < 4; ++nf)
        sacc[nf] = __builtin_amdgcn_mfma_f32_16x16x32_bf16(qf[kk], kf[nf],
                                                           sacc[nf], 0, 0, 0);
    }

    // scale*aw (prefetched), mask, online softmax; P -> per-wave LDS tile
    float alpha[4];
#pragma unroll
    for (int j = 0; j < 4; ++j) {
      float mx = -1e30f;
#pragma unroll
      for (int nf = 0; nf < 4; ++nf) {
        float s = sacc[nf][j] * scale * awc[j][nf];
        s = ((mkc[j] >> nf) & 1u) ? -1e30f : s;
        sacc[nf][j] = s;
        mx = fmaxf(mx, s);
      }
      mx = fmaxf(mx, __shfl_xor(mx, 1));
      mx = fmaxf(mx, __shfl_xor(mx, 2));
      mx = fmaxf(mx, __shfl_xor(mx, 4));
      mx = fmaxf(mx, __shfl_xor(mx, 8));
      float mnew = fmaxf(mrun[j], mx);
      float al = __expf(mrun[j] - mnew);
      mrun[j] = mnew;
      float psum = 0.f;
      const int prow = lg * 4 + j;
      const int swp = (prow & 7) << 4;
#pragma unroll
      for (int nf = 0; nf < 4; ++nf) {
        float s = sacc[nf][j];
        float p = (s <= -1e29f) ? 0.f : __expf(s - mnew);
        psum += p;
        *(unsigned short*)((char*)lP[wave] + prow * 128 +
                           (((nf * 16 + l15) * 2) ^ swp)) = f2bf(p);
      }
      psum += __shfl_xor(psum, 1);
      psum += __shfl_xor(psum, 2);
      psum += __shfl_xor(psum, 4);
      psum += __shfl_xor(psum, 8);
      lrun[j] = lrun[j] * al + psum;
      alpha[j] = al;
    }
#pragma unroll
    for (int df = 0; df < 4; ++df)
#pragma unroll
      for (int j = 0; j < 4; ++j) oacc[df][j] *= alpha[j];

    // O += P @ V  (both from LDS)
#pragma unroll
    for (int kk2 = 0; kk2 < 2; ++kk2) {
      bf16x8 pf;
      {
        int off = (kk2 * 64 + lg * 16) ^ ((l15 & 7) << 4);
        pf = *(const bf16x8*)((const char*)lP[wave] + l15 * 128 + off);
      }
#pragma unroll
      for (int df = 0; df < 4; ++df) {
        int row = df * 16 + l15;
        int off = (kk2 * 64 + lg * 16) ^ ((row & 7) << 4);
        bf16x8 vf = *(const bf16x8*)((const char*)lV[cur] + row * 128 + off);
        oacc[df] = __builtin_amdgcn_mfma_f32_16x16x32_bf16(pf, vf,
                                                           oacc[df], 0, 0, 0);
      }
    }
    __syncthreads();  // next K/V tiles staged; all lK/lV[cur]/lP reads done
  }

  // epilogue: write bf16 partial O + fp32 (m,l)
#pragma unroll
  for (int j = 0; j < 4; ++j) {
    const int r = qrow0 + lg * 4 + j;
    const size_t row = (size_t)bh * 1024 + r;
    if (l15 == 0) stats[(size_t)half * 65536 + row] = make_float2(mrun[j], lrun[j]);
#pragma unroll
    for (int df = 0; df < 4; ++df)
      opart[((size_t)half * 65536 + row) * 64 + df * 16 + l15] =
          f2bf(oacc[df][j]);
  }
}

// ---------------- flash-merge of the two kt-halves ----------------
__global__ __launch_bounds__(256) void merge_kernel(
    const unsigned short* __restrict__ opart, const float2* __restrict__ stats,
    unsigned short* __restrict__ attnout) {
  const int idx = blockIdx.x * 256 + threadIdx.x;  // 524288 threads
  const int row = idx >> 3, seg = idx & 7;
  float2 s0 = stats[row], s1 = stats[65536 + row];
  float M = fmaxf(s0.x, s1.x);
  float a0 = __expf(s0.x - M), a1 = __expf(s1.x - M);
  float inv = 1.0f / (s0.y * a0 + s1.y * a1);
  bf16x8 O0 = *(const bf16x8*)&opart[(size_t)row * 64 + seg * 8];
  bf16x8 O1 = *(const bf16x8*)&opart[(size_t)(65536 + row) * 64 + seg * 8];
  const int bh = row >> 10, qq = row & 1023;
  const int b = bh >> 4, h = bh & 15;
  bf16x8 o;
#pragma unroll
  for (int j = 0; j < 8; ++j)
    o[j] = (short)f2bf((bf2f((unsigned short)O0[j]) * a0 +
                        bf2f((unsigned short)O1[j]) * a1) * inv);
  *(bf16x8*)&attnout[(size_t)(b * 1024 + qq) * 1024 + h * 64 + seg * 8] = o;
}

extern "C" void kernel_launch(void* const* d_in, const int* in_sizes, int n_in,
                              void* d_out, int out_size, void* d_ws, size_t ws_size,
                              hipStream_t stream) {
  const float* queries = (const float*)d_in[0];
  const float* keys1 = (const float*)d_in[1];
  const float* keys2 = (const float*)d_in[2];
  const float* values = (const float*)d_in[3];
  const float* aw = (const float*)d_in[4];
  const void* mask = d_in[5];
  const float* Wq = (const float*)d_in[6];
  const float* bq = (const float*)d_in[7];
  const float* Wk1 = (const float*)d_in[8];
  const float* bk1 = (const float*)d_in[9];
  const float* Wk2 = (const float*)d_in[10];
  const float* bk2 = (const float*)d_in[11];
  const float* Wv = (const float*)d_in[12];
  const float* bv = (const float*)d_in[13];
  const float* Wo = (const float*)d_in[14];
  const float* bo = (const float*)d_in[15];

  char* ws = (char*)d_ws;
  unsigned short* qbf = (unsigned short*)(ws + (0ull << 20));
  unsigned short* khat = (unsigned short*)(ws + (8ull << 20));
  unsigned short* vTb = (unsigned short*)(ws + (16ull << 20));
  unsigned short* attno = (unsigned short*)(ws + (24ull << 20));
  unsigned short* WT = (unsigned short*)(ws + (32ull << 20));
  unsigned short* WoT = WT;                   // z=0 at 32 MiB (survives attn)
  unsigned short* WqT = WT + 1 * 1048576;     // 34 MiB
  unsigned short* Wk1T = WT + 2 * 1048576;    // 36
  unsigned short* Wk2T = WT + 3 * 1048576;    // 38
  unsigned short* WvT = WT + 4 * 1048576;     // 40
  unsigned short* opart = (unsigned short*)(ws + (34ull << 20));  // 16 MiB
  float2* stats = (float2*)(ws + (50ull << 20));                  // 1 MiB

  transpose5_kernel<<<dim3(32, 32, 5), 256, 0, stream>>>(
      W5{Wo, Wq, Wk1, Wk2, Wv}, WT);

  const dim3 gg(64, 16);  // M/64, N/64
  gemm64_kernel<0><<<gg, 256, 0, stream>>>(queries, WqT, nullptr, nullptr,
                                           bq, nullptr, qbf, 4096, 1024, 1024, 0);
  gemm64_kernel<0><<<gg, 256, 0, stream>>>(keys1, Wk1T, keys2, Wk2T,
                                           bk1, bk2, khat, 4096, 1024, 1024, 0);
  gemm64_kernel<0><<<gg, 256, 0, stream>>>(values, WvT, nullptr, nullptr,
                                           bv, nullptr, vTb, 4096, 1024, 1024, 1);

  attn_kernel<<<2048, 256, 0, stream>>>(qbf, khat, vTb, aw, mask, opart, stats);
  merge_kernel<<<2048, 256, 0, stream>>>(opart, stats, attno);

  gemm64_kernel<1><<<gg, 256, 0, stream>>>(attno, WoT, nullptr, nullptr,
                                           bo, nullptr, d_out, 4096, 1024, 1024, 2);
}